// Round 23
// baseline (66.780 us; speedup 1.0000x reference)
//
#include <hip/hip_runtime.h>

#define BATCH 16
#define SEQ   1024
#define DM    512
#define NST   32
#define PF    8     // x-prefetch block

// ws layout: [dA_tbl][Cw_tbl][p_tbl] (each 2*NST*DM) [E 2*BATCH*nc*NST*DM]
// E: [ssm][b][c][n][d] = chunk-END local states from pass1 (c < nc-1).
// pass3 reconstructs chunk-INIT via Horner over E with p = dA^cl (no pass2).

// ---------------- fallback setup (only used if nc==1): tables [ssm][n][d]
__global__ __launch_bounds__(256) void ssm_setup(
    const float* __restrict__ Alog_hr, const float* __restrict__ B_hr,
    const float* __restrict__ C_hr,    const float* __restrict__ ldt_hr,
    const float* __restrict__ Alog_br, const float* __restrict__ B_br,
    const float* __restrict__ C_br,    const float* __restrict__ ldt_br,
    const float* __restrict__ w_hr,    const float* __restrict__ w_br,
    float* __restrict__ dA_tbl, float* __restrict__ Cw_tbl)
{
    int idx = blockIdx.x * blockDim.x + threadIdx.x;   // (ssm*NST + n)*DM + d
    int d   = idx & (DM - 1);
    int n   = (idx >> 9) & (NST - 1);
    int ssm = idx >> 14;

    const float* Alog = ssm ? Alog_br : Alog_hr;
    const float* Bm   = ssm ? B_br    : B_hr;
    const float* Cm   = ssm ? C_br    : C_hr;
    const float* ldt  = ssm ? ldt_br  : ldt_hr;
    const float* w    = ssm ? w_br    : w_hr;

    float dt = expf(ldt[d]);
    float a  = expf(Alog[d * NST + n]);
    dA_tbl[idx] = expf(dt * a);
    Cw_tbl[idx] = Cm[d * NST + n] * Bm[d * NST + n] * dt * w[d];
}

// ---------------- pass 1: local chunk scans (c<nc-1) + table writes from (b==0,c==0) blocks
__global__ __launch_bounds__(256) void ssm_pass1(
    const float* __restrict__ x,
    const float* __restrict__ Alog_hr, const float* __restrict__ B_hr,
    const float* __restrict__ C_hr,    const float* __restrict__ ldt_hr,
    const float* __restrict__ Alog_br, const float* __restrict__ B_br,
    const float* __restrict__ C_br,    const float* __restrict__ ldt_br,
    const float* __restrict__ w_hr,    const float* __restrict__ w_br,
    float* __restrict__ E,
    float* __restrict__ dA_tbl, float* __restrict__ Cw_tbl, float* __restrict__ p_tbl,
    int nc, int cl)
{
    int tid  = threadIdx.x;
    int dlo  = tid & 127;
    int nh   = tid >> 7;            // n-half
    int bid  = blockIdx.x;          // ((ssm*BATCH+b)*(nc-1) + c)*4 + dblk
    int dblk = bid & 3;
    int r    = bid >> 2;
    int ncm1 = nc - 1;
    int c    = r % ncm1;  r /= ncm1;
    int b    = r & (BATCH - 1);
    int ssm  = r >> 4;
    int d    = dblk * 128 + dlo;
    int n0   = nh * 16;

    const float* Alog = ssm ? Alog_br : Alog_hr;
    const float* ldt  = ssm ? ldt_br  : ldt_hr;

    float dt = expf(ldt[d]);
    float dA[16], g[16];
#pragma unroll
    for (int i = 0; i < 16; ++i) {
        dA[i] = expf(dt * expf(Alog[d * NST + n0 + i]));
        g[i]  = 0.f;
    }

    if (b == 0 && c == 0) {          // 8 blocks write the [ssm][n][d] tables
        const float* Bm = ssm ? B_br : B_hr;
        const float* Cm = ssm ? C_br : C_hr;
        const float* w  = ssm ? w_br : w_hr;
        float wd = w[d];
        float clf = (float)cl;
#pragma unroll
        for (int i = 0; i < 16; ++i) {
            float a = expf(Alog[d * NST + n0 + i]);
            int tix = (ssm * NST + n0 + i) * DM + d;
            dA_tbl[tix] = dA[i];
            p_tbl[tix]  = expf(clf * dt * a);    // dA^cl
            Cw_tbl[tix] = Cm[d * NST + n0 + i] * Bm[d * NST + n0 + i] * dt * wd;
        }
    }

    const float* xp = x + ((size_t)b * SEQ + (size_t)c * cl) * DM + d;

    float xf[PF];
#pragma unroll
    for (int k = 0; k < PF; ++k) xf[k] = xp[(size_t)k * DM];
    const float* xq = xp + (size_t)PF * DM;

    int ntb = cl / PF;
    for (int t8 = 0; t8 < ntb - 1; ++t8) {
#pragma unroll
        for (int j = 0; j < PF; ++j) {
            float xv = xf[j];
            xf[j] = xq[(size_t)j * DM];          // prefetch t+PF
#pragma unroll
            for (int i = 0; i < 16; ++i) g[i] = fmaf(dA[i], g[i], xv);
        }
        xq += (size_t)PF * DM;
    }
#pragma unroll
    for (int j = 0; j < PF; ++j) {               // tail: no prefetch
        float xv = xf[j];
#pragma unroll
        for (int i = 0; i < 16; ++i) g[i] = fmaf(dA[i], g[i], xv);
    }

    float* sp = E + ((((size_t)ssm * BATCH + b) * nc + c) * NST + n0) * DM + d;
#pragma unroll
    for (int i = 0; i < 16; ++i) sp[(size_t)i * DM] = g[i];
}

// ---------------- pass 3: ssm-split wave halves; xf prefetch issued BEFORE the Horner
// prologue (independent streams overlap); c mapped DESCENDING so long-Horner blocks
// launch first (tail balance); R22 t-loop body unchanged.
__global__ __launch_bounds__(128, 2) void ssm_pass3(
    const float* __restrict__ x,
    const float* __restrict__ dA_tbl, const float* __restrict__ Cw_tbl,
    const float* __restrict__ p_tbl,
    const float* __restrict__ E,
    float* __restrict__ out_hr, float* __restrict__ out_br, float* __restrict__ out_cb,
    int nc, int cl)
{
    int tid  = threadIdx.x;          // 128 threads = 2 waves
    int lane = tid & 63;
    int wid  = tid >> 6;
    int ssm  = lane >> 5;            // 0 -> hr, 1 -> br
    int dlo  = lane & 31;
    int bid  = blockIdx.x;           // (b*nc + cq)*8 + dblk, c = nc-1-cq (descending)
    int dblk = bid & 7;
    int r    = bid >> 3;
    int c    = nc - 1 - (r % nc);    // long-Horner blocks first
    int b    = r / nc;
    int d    = dblk * 64 + wid * 32 + dlo;

    size_t off = ((size_t)b * SEQ + (size_t)c * cl) * DM + d;
    const float* xp = x + off;

    // issue the x-stream prefetch FIRST: independent of Horner, overlaps its L2 chain
    float xf[PF];
#pragma unroll
    for (int k = 0; k < PF; ++k) xf[k] = xp[(size_t)k * DM];
    const float* xq = xp + (size_t)PF * DM;

    // ----- chunk-INIT via Horner over local end-states (replaces pass2)
    float g[NST];
#pragma unroll
    for (int n = 0; n < NST; ++n) g[n] = 0.f;
    if (c > 0) {
        const float* pt = p_tbl + (size_t)ssm * NST * DM + d;
        float p[NST];
#pragma unroll
        for (int n = 0; n < NST; ++n) p[n] = pt[(size_t)n * DM];
        const size_t slab = (size_t)NST * DM;
        const float* ep = E + (((size_t)ssm * BATCH + b) * nc) * slab + d;
        for (int cc = 0; cc < c; ++cc) {        // g = p*g + E(cc), loads folded in
#pragma unroll
            for (int n = 0; n < NST; ++n)
                g[n] = fmaf(p[n], g[n], ep[(size_t)n * DM]);
            ep += slab;
        }
    }

    const float* dat = dA_tbl + (size_t)ssm * NST * DM + d;
    const float* cwt = Cw_tbl + (size_t)ssm * NST * DM + d;
    float dA[NST], Cw[NST];
#pragma unroll
    for (int n = 0; n < NST; ++n) {
        dA[n] = dat[(size_t)n * DM];
        Cw[n] = cwt[(size_t)n * DM];
    }

    float* po = (ssm ? out_br : out_hr) + off;   // primary: full-wave store
    float* oc = out_cb + off;                    // combined: masked to ssm==0 half

    // DOPF: 1 -> batched reload at block top, 0 -> tail
#define BODY8(DOPF)                                                     \
    {                                                                   \
        float xc[PF];                                                   \
        _Pragma("unroll")                                               \
        for (int j = 0; j < PF; ++j) xc[j] = xf[j];                     \
        if (DOPF) {                           /* batched load issue */  \
            _Pragma("unroll")                                           \
            for (int j = 0; j < PF; ++j) xf[j] = xq[(size_t)j * DM];    \
        }                                                               \
        float yv[PF], yw[PF];                                           \
        _Pragma("unroll")                                               \
        for (int j = 0; j < PF; ++j) {                                  \
            float xv = xc[j];                                           \
            float y0 = 0.f, y1 = 0.f, y2 = 0.f, y3 = 0.f;               \
            _Pragma("unroll")                                           \
            for (int n = 0; n < NST; n += 4) {                          \
                g[n]     = fmaf(dA[n],     g[n],     xv);               \
                g[n + 1] = fmaf(dA[n + 1], g[n + 1], xv);               \
                g[n + 2] = fmaf(dA[n + 2], g[n + 2], xv);               \
                g[n + 3] = fmaf(dA[n + 3], g[n + 3], xv);               \
                y0 = fmaf(Cw[n],     g[n],     y0);                     \
                y1 = fmaf(Cw[n + 1], g[n + 1], y1);                     \
                y2 = fmaf(Cw[n + 2], g[n + 2], y2);                     \
                y3 = fmaf(Cw[n + 3], g[n + 3], y3);                     \
            }                                                           \
            float y = (y0 + y1) + (y2 + y3);                            \
            yv[j] = y;                                                  \
            yw[j] = __shfl_xor(y, 32, 64);   /* no use until batch */   \
            po[(size_t)j * DM] = y;          /* full-wave store */      \
        }                                                               \
        if (ssm == 0) {                       /* batched combined */    \
            _Pragma("unroll")                                           \
            for (int j = 0; j < PF; ++j)                                \
                oc[(size_t)j * DM] = yv[j] + yw[j];                     \
        }                                                               \
        po += (size_t)PF * DM;  oc += (size_t)PF * DM;                  \
    }

    int ntb = cl / PF;
    for (int t8 = 0; t8 < ntb - 1; ++t8) {
        BODY8(1);
        xq += (size_t)PF * DM;
    }
    BODY8(0);
#undef BODY8
}

extern "C" void kernel_launch(void* const* d_in, const int* in_sizes, int n_in,
                              void* d_out, int out_size, void* d_ws, size_t ws_size,
                              hipStream_t stream)
{
    (void)in_sizes; (void)n_in; (void)out_size;

    const float* x       = (const float*)d_in[0];
    const float* Alog_hr = (const float*)d_in[1];
    const float* B_hr    = (const float*)d_in[2];
    const float* C_hr    = (const float*)d_in[3];
    const float* ldt_hr  = (const float*)d_in[4];
    const float* Alog_br = (const float*)d_in[5];
    const float* B_br    = (const float*)d_in[6];
    const float* C_br    = (const float*)d_in[7];
    const float* ldt_br  = (const float*)d_in[8];
    const float* w_hr    = (const float*)d_in[9];
    const float* w_br    = (const float*)d_in[10];

    float* out    = (float*)d_out;
    const size_t one = (size_t)BATCH * SEQ * DM;
    float* out_hr = out;
    float* out_br = out + one;
    float* out_cb = out + 2 * one;

    float* dA_tbl = (float*)d_ws;
    float* Cw_tbl = dA_tbl + (size_t)2 * NST * DM;
    float* p_tbl  = Cw_tbl + (size_t)2 * NST * DM;
    float* E      = p_tbl  + (size_t)2 * NST * DM;

    const size_t tbl_bytes = (size_t)6 * NST * DM * sizeof(float);
    int nc = 8;      // proven; nc=16 dead (R11, R17, R20; Horner cost ~ nc^2)
    while (nc > 1 &&
           ws_size < tbl_bytes + (size_t)2 * BATCH * nc * NST * DM * sizeof(float))
        nc >>= 1;
    int cl = SEQ / nc;

    if (nc > 1) {
        int nblk1 = 2 * BATCH * (nc - 1) * 4;    // (ssm,b,c<nc-1) x 4 d-blocks of 128 (x2 nh)
        ssm_pass1<<<nblk1, 256, 0, stream>>>(x,
                                             Alog_hr, B_hr, C_hr, ldt_hr,
                                             Alog_br, B_br, C_br, ldt_br,
                                             w_hr, w_br,
                                             E, dA_tbl, Cw_tbl, p_tbl, nc, cl);
    } else {
        int total0 = 2 * NST * DM;               // fallback: tables via setup
        ssm_setup<<<total0 / 256, 256, 0, stream>>>(Alog_hr, B_hr, C_hr, ldt_hr,
                                                    Alog_br, B_br, C_br, ldt_br,
                                                    w_hr, w_br, dA_tbl, Cw_tbl);
    }

    int nblk3 = BATCH * nc * 8;                  // (b,c) x 8 d-blocks of 64 (2 waves, ssm-split)
    ssm_pass3<<<nblk3, 128, 0, stream>>>(x, dA_tbl, Cw_tbl, p_tbl, E,
                                         out_hr, out_br, out_cb, nc, cl);
}

// Round 24
// 65.451 us; speedup vs baseline: 1.0203x; 1.0203x over previous
//
#include <hip/hip_runtime.h>

#define BATCH 16
#define SEQ   1024
#define DM    512
#define NST   32
#define PF    8     // x-prefetch block

// ws layout: [dA_tbl][Cw_tbl][p_tbl] (each 2*NST*DM) [E 2*BATCH*nc*NST*DM]
// E: [ssm][b][c][n][d] = chunk-END local states from pass1 (c < nc-1).
// pass3 reconstructs chunk-INIT via Horner over E with p = dA^cl (no pass2).

// ---------------- fallback setup (only used if nc==1): tables [ssm][n][d]
__global__ __launch_bounds__(256) void ssm_setup(
    const float* __restrict__ Alog_hr, const float* __restrict__ B_hr,
    const float* __restrict__ C_hr,    const float* __restrict__ ldt_hr,
    const float* __restrict__ Alog_br, const float* __restrict__ B_br,
    const float* __restrict__ C_br,    const float* __restrict__ ldt_br,
    const float* __restrict__ w_hr,    const float* __restrict__ w_br,
    float* __restrict__ dA_tbl, float* __restrict__ Cw_tbl)
{
    int idx = blockIdx.x * blockDim.x + threadIdx.x;   // (ssm*NST + n)*DM + d
    int d   = idx & (DM - 1);
    int n   = (idx >> 9) & (NST - 1);
    int ssm = idx >> 14;

    const float* Alog = ssm ? Alog_br : Alog_hr;
    const float* Bm   = ssm ? B_br    : B_hr;
    const float* Cm   = ssm ? C_br    : C_hr;
    const float* ldt  = ssm ? ldt_br  : ldt_hr;
    const float* w    = ssm ? w_br    : w_hr;

    float dt = expf(ldt[d]);
    float a  = expf(Alog[d * NST + n]);
    dA_tbl[idx] = expf(dt * a);
    Cw_tbl[idx] = Cm[d * NST + n] * Bm[d * NST + n] * dt * w[d];
}

// ---------------- pass 1: local chunk scans (c<nc-1) + table writes from (b==0,c==0) blocks
__global__ __launch_bounds__(256) void ssm_pass1(
    const float* __restrict__ x,
    const float* __restrict__ Alog_hr, const float* __restrict__ B_hr,
    const float* __restrict__ C_hr,    const float* __restrict__ ldt_hr,
    const float* __restrict__ Alog_br, const float* __restrict__ B_br,
    const float* __restrict__ C_br,    const float* __restrict__ ldt_br,
    const float* __restrict__ w_hr,    const float* __restrict__ w_br,
    float* __restrict__ E,
    float* __restrict__ dA_tbl, float* __restrict__ Cw_tbl, float* __restrict__ p_tbl,
    int nc, int cl)
{
    int tid  = threadIdx.x;
    int dlo  = tid & 127;
    int nh   = tid >> 7;            // n-half
    int bid  = blockIdx.x;          // ((ssm*BATCH+b)*(nc-1) + c)*4 + dblk
    int dblk = bid & 3;
    int r    = bid >> 2;
    int ncm1 = nc - 1;
    int c    = r % ncm1;  r /= ncm1;
    int b    = r & (BATCH - 1);
    int ssm  = r >> 4;
    int d    = dblk * 128 + dlo;
    int n0   = nh * 16;

    const float* Alog = ssm ? Alog_br : Alog_hr;
    const float* ldt  = ssm ? ldt_br  : ldt_hr;

    float dt = expf(ldt[d]);
    float dA[16], g[16];
#pragma unroll
    for (int i = 0; i < 16; ++i) {
        dA[i] = expf(dt * expf(Alog[d * NST + n0 + i]));
        g[i]  = 0.f;
    }

    if (b == 0 && c == 0) {          // 8 blocks write the [ssm][n][d] tables
        const float* Bm = ssm ? B_br : B_hr;
        const float* Cm = ssm ? C_br : C_hr;
        const float* w  = ssm ? w_br : w_hr;
        float wd = w[d];
        float clf = (float)cl;
#pragma unroll
        for (int i = 0; i < 16; ++i) {
            float a = expf(Alog[d * NST + n0 + i]);
            int tix = (ssm * NST + n0 + i) * DM + d;
            dA_tbl[tix] = dA[i];
            p_tbl[tix]  = expf(clf * dt * a);    // dA^cl
            Cw_tbl[tix] = Cm[d * NST + n0 + i] * Bm[d * NST + n0 + i] * dt * wd;
        }
    }

    const float* xp = x + ((size_t)b * SEQ + (size_t)c * cl) * DM + d;

    float xf[PF];
#pragma unroll
    for (int k = 0; k < PF; ++k) xf[k] = xp[(size_t)k * DM];
    const float* xq = xp + (size_t)PF * DM;

    int ntb = cl / PF;
    for (int t8 = 0; t8 < ntb - 1; ++t8) {
#pragma unroll
        for (int j = 0; j < PF; ++j) {
            float xv = xf[j];
            xf[j] = xq[(size_t)j * DM];          // prefetch t+PF
#pragma unroll
            for (int i = 0; i < 16; ++i) g[i] = fmaf(dA[i], g[i], xv);
        }
        xq += (size_t)PF * DM;
    }
#pragma unroll
    for (int j = 0; j < PF; ++j) {               // tail: no prefetch
        float xv = xf[j];
#pragma unroll
        for (int i = 0; i < 16; ++i) g[i] = fmaf(dA[i], g[i], xv);
    }

    float* sp = E + ((((size_t)ssm * BATCH + b) * nc + c) * NST + n0) * DM + d;
#pragma unroll
    for (int i = 0; i < 16; ++i) sp[(size_t)i * DM] = g[i];
}

// ---------------- pass 3: R22 structure (best: 63.7 us) + s_setprio around the FMA
// cluster. Waves are independent (no barriers) -> the regime where setprio helps
// (attn m191 +4-7%), unlike lockstep GEMM (m190 null).
__global__ __launch_bounds__(128, 2) void ssm_pass3(
    const float* __restrict__ x,
    const float* __restrict__ dA_tbl, const float* __restrict__ Cw_tbl,
    const float* __restrict__ p_tbl,
    const float* __restrict__ E,
    float* __restrict__ out_hr, float* __restrict__ out_br, float* __restrict__ out_cb,
    int nc, int cl)
{
    int tid  = threadIdx.x;          // 128 threads = 2 waves
    int lane = tid & 63;
    int wid  = tid >> 6;
    int ssm  = lane >> 5;            // 0 -> hr, 1 -> br
    int dlo  = lane & 31;
    int bid  = blockIdx.x;           // (b*nc + c)*8 + dblk
    int dblk = bid & 7;
    int r    = bid >> 3;
    int c    = r % nc;
    int b    = r / nc;
    int d    = dblk * 64 + wid * 32 + dlo;

    // ----- chunk-INIT via Horner over local end-states (replaces pass2)
    float g[NST];
#pragma unroll
    for (int n = 0; n < NST; ++n) g[n] = 0.f;
    if (c > 0) {
        const float* pt = p_tbl + (size_t)ssm * NST * DM + d;
        float p[NST];
#pragma unroll
        for (int n = 0; n < NST; ++n) p[n] = pt[(size_t)n * DM];
        const size_t slab = (size_t)NST * DM;
        const float* ep = E + (((size_t)ssm * BATCH + b) * nc) * slab + d;
        for (int cc = 0; cc < c; ++cc) {        // g = p*g + E(cc), loads folded in
#pragma unroll
            for (int n = 0; n < NST; ++n)
                g[n] = fmaf(p[n], g[n], ep[(size_t)n * DM]);
            ep += slab;
        }
    }

    const float* dat = dA_tbl + (size_t)ssm * NST * DM + d;
    const float* cwt = Cw_tbl + (size_t)ssm * NST * DM + d;
    float dA[NST], Cw[NST];
#pragma unroll
    for (int n = 0; n < NST; ++n) {
        dA[n] = dat[(size_t)n * DM];
        Cw[n] = cwt[(size_t)n * DM];
    }

    size_t off = ((size_t)b * SEQ + (size_t)c * cl) * DM + d;
    const float* xp = x + off;
    float* po = (ssm ? out_br : out_hr) + off;   // primary: full-wave store
    float* oc = out_cb + off;                    // combined: masked to ssm==0 half

    float xf[PF];
#pragma unroll
    for (int k = 0; k < PF; ++k) xf[k] = xp[(size_t)k * DM];
    const float* xq = xp + (size_t)PF * DM;

    // DOPF: 1 -> batched reload at block top, 0 -> tail
#define BODY8(DOPF)                                                     \
    {                                                                   \
        float xc[PF];                                                   \
        _Pragma("unroll")                                               \
        for (int j = 0; j < PF; ++j) xc[j] = xf[j];                     \
        if (DOPF) {                           /* batched load issue */  \
            _Pragma("unroll")                                           \
            for (int j = 0; j < PF; ++j) xf[j] = xq[(size_t)j * DM];    \
        }                                                               \
        float yv[PF], yw[PF];                                           \
        __builtin_amdgcn_s_setprio(1);        /* favor compute wave */  \
        _Pragma("unroll")                                               \
        for (int j = 0; j < PF; ++j) {                                  \
            float xv = xc[j];                                           \
            float y0 = 0.f, y1 = 0.f, y2 = 0.f, y3 = 0.f;               \
            _Pragma("unroll")                                           \
            for (int n = 0; n < NST; n += 4) {                          \
                g[n]     = fmaf(dA[n],     g[n],     xv);               \
                g[n + 1] = fmaf(dA[n + 1], g[n + 1], xv);               \
                g[n + 2] = fmaf(dA[n + 2], g[n + 2], xv);               \
                g[n + 3] = fmaf(dA[n + 3], g[n + 3], xv);               \
                y0 = fmaf(Cw[n],     g[n],     y0);                     \
                y1 = fmaf(Cw[n + 1], g[n + 1], y1);                     \
                y2 = fmaf(Cw[n + 2], g[n + 2], y2);                     \
                y3 = fmaf(Cw[n + 3], g[n + 3], y3);                     \
            }                                                           \
            float y = (y0 + y1) + (y2 + y3);                            \
            yv[j] = y;                                                  \
            yw[j] = __shfl_xor(y, 32, 64);   /* no use until batch */   \
            po[(size_t)j * DM] = y;          /* full-wave store */      \
        }                                                               \
        __builtin_amdgcn_s_setprio(0);                                  \
        if (ssm == 0) {                       /* batched combined */    \
            _Pragma("unroll")                                           \
            for (int j = 0; j < PF; ++j)                                \
                oc[(size_t)j * DM] = yv[j] + yw[j];                     \
        }                                                               \
        po += (size_t)PF * DM;  oc += (size_t)PF * DM;                  \
    }

    int ntb = cl / PF;
    for (int t8 = 0; t8 < ntb - 1; ++t8) {
        BODY8(1);
        xq += (size_t)PF * DM;
    }
    BODY8(0);
#undef BODY8
}

extern "C" void kernel_launch(void* const* d_in, const int* in_sizes, int n_in,
                              void* d_out, int out_size, void* d_ws, size_t ws_size,
                              hipStream_t stream)
{
    (void)in_sizes; (void)n_in; (void)out_size;

    const float* x       = (const float*)d_in[0];
    const float* Alog_hr = (const float*)d_in[1];
    const float* B_hr    = (const float*)d_in[2];
    const float* C_hr    = (const float*)d_in[3];
    const float* ldt_hr  = (const float*)d_in[4];
    const float* Alog_br = (const float*)d_in[5];
    const float* B_br    = (const float*)d_in[6];
    const float* C_br    = (const float*)d_in[7];
    const float* ldt_br  = (const float*)d_in[8];
    const float* w_hr    = (const float*)d_in[9];
    const float* w_br    = (const float*)d_in[10];

    float* out    = (float*)d_out;
    const size_t one = (size_t)BATCH * SEQ * DM;
    float* out_hr = out;
    float* out_br = out + one;
    float* out_cb = out + 2 * one;

    float* dA_tbl = (float*)d_ws;
    float* Cw_tbl = dA_tbl + (size_t)2 * NST * DM;
    float* p_tbl  = Cw_tbl + (size_t)2 * NST * DM;
    float* E      = p_tbl  + (size_t)2 * NST * DM;

    const size_t tbl_bytes = (size_t)6 * NST * DM * sizeof(float);
    int nc = 8;      // proven; nc=16 dead (R11, R17, R20; Horner cost ~ nc^2)
    while (nc > 1 &&
           ws_size < tbl_bytes + (size_t)2 * BATCH * nc * NST * DM * sizeof(float))
        nc >>= 1;
    int cl = SEQ / nc;

    if (nc > 1) {
        int nblk1 = 2 * BATCH * (nc - 1) * 4;    // (ssm,b,c<nc-1) x 4 d-blocks of 128 (x2 nh)
        ssm_pass1<<<nblk1, 256, 0, stream>>>(x,
                                             Alog_hr, B_hr, C_hr, ldt_hr,
                                             Alog_br, B_br, C_br, ldt_br,
                                             w_hr, w_br,
                                             E, dA_tbl, Cw_tbl, p_tbl, nc, cl);
    } else {
        int total0 = 2 * NST * DM;               // fallback: tables via setup
        ssm_setup<<<total0 / 256, 256, 0, stream>>>(Alog_hr, B_hr, C_hr, ldt_hr,
                                                    Alog_br, B_br, C_br, ldt_br,
                                                    w_hr, w_br, dA_tbl, Cw_tbl);
    }

    int nblk3 = BATCH * nc * 8;                  // (b,c) x 8 d-blocks of 64 (2 waves, ssm-split)
    ssm_pass3<<<nblk3, 128, 0, stream>>>(x, dA_tbl, Cw_tbl, p_tbl, E,
                                         out_hr, out_br, out_cb, nc, cl);
}

// Round 25
// 63.096 us; speedup vs baseline: 1.0584x; 1.0373x over previous
//
#include <hip/hip_runtime.h>

#define BATCH 16
#define SEQ   1024
#define DM    512
#define NST   32
#define PF    8     // x-prefetch block

// ws layout: [dA_tbl][Cw_tbl][p_tbl] (each 2*NST*DM) [E 2*BATCH*nc*NST*DM]
// E: [ssm][b][c][n][d] = chunk-END local states from pass1 (c < nc-1).
// pass3 reconstructs chunk-INIT via Horner over E with p = dA^cl (no pass2).

// ---------------- fallback setup (only used if nc==1): tables [ssm][n][d]
__global__ __launch_bounds__(256) void ssm_setup(
    const float* __restrict__ Alog_hr, const float* __restrict__ B_hr,
    const float* __restrict__ C_hr,    const float* __restrict__ ldt_hr,
    const float* __restrict__ Alog_br, const float* __restrict__ B_br,
    const float* __restrict__ C_br,    const float* __restrict__ ldt_br,
    const float* __restrict__ w_hr,    const float* __restrict__ w_br,
    float* __restrict__ dA_tbl, float* __restrict__ Cw_tbl)
{
    int idx = blockIdx.x * blockDim.x + threadIdx.x;   // (ssm*NST + n)*DM + d
    int d   = idx & (DM - 1);
    int n   = (idx >> 9) & (NST - 1);
    int ssm = idx >> 14;

    const float* Alog = ssm ? Alog_br : Alog_hr;
    const float* Bm   = ssm ? B_br    : B_hr;
    const float* Cm   = ssm ? C_br    : C_hr;
    const float* ldt  = ssm ? ldt_br  : ldt_hr;
    const float* w    = ssm ? w_br    : w_hr;

    float dt = expf(ldt[d]);
    float a  = expf(Alog[d * NST + n]);
    dA_tbl[idx] = expf(dt * a);
    Cw_tbl[idx] = Cm[d * NST + n] * Bm[d * NST + n] * dt * w[d];
}

// ---------------- pass 1: local chunk scans (c<nc-1) + table writes from (b==0,c==0) blocks
__global__ __launch_bounds__(256) void ssm_pass1(
    const float* __restrict__ x,
    const float* __restrict__ Alog_hr, const float* __restrict__ B_hr,
    const float* __restrict__ C_hr,    const float* __restrict__ ldt_hr,
    const float* __restrict__ Alog_br, const float* __restrict__ B_br,
    const float* __restrict__ C_br,    const float* __restrict__ ldt_br,
    const float* __restrict__ w_hr,    const float* __restrict__ w_br,
    float* __restrict__ E,
    float* __restrict__ dA_tbl, float* __restrict__ Cw_tbl, float* __restrict__ p_tbl,
    int nc, int cl)
{
    int tid  = threadIdx.x;
    int dlo  = tid & 127;
    int nh   = tid >> 7;            // n-half
    int bid  = blockIdx.x;          // ((ssm*BATCH+b)*(nc-1) + c)*4 + dblk
    int dblk = bid & 3;
    int r    = bid >> 2;
    int ncm1 = nc - 1;
    int c    = r % ncm1;  r /= ncm1;
    int b    = r & (BATCH - 1);
    int ssm  = r >> 4;
    int d    = dblk * 128 + dlo;
    int n0   = nh * 16;

    const float* Alog = ssm ? Alog_br : Alog_hr;
    const float* ldt  = ssm ? ldt_br  : ldt_hr;

    float dt = expf(ldt[d]);
    float dA[16], g[16];
#pragma unroll
    for (int i = 0; i < 16; ++i) {
        dA[i] = expf(dt * expf(Alog[d * NST + n0 + i]));
        g[i]  = 0.f;
    }

    if (b == 0 && c == 0) {          // 8 blocks write the [ssm][n][d] tables
        const float* Bm = ssm ? B_br : B_hr;
        const float* Cm = ssm ? C_br : C_hr;
        const float* w  = ssm ? w_br : w_hr;
        float wd = w[d];
        float clf = (float)cl;
#pragma unroll
        for (int i = 0; i < 16; ++i) {
            float a = expf(Alog[d * NST + n0 + i]);
            int tix = (ssm * NST + n0 + i) * DM + d;
            dA_tbl[tix] = dA[i];
            p_tbl[tix]  = expf(clf * dt * a);    // dA^cl
            Cw_tbl[tix] = Cm[d * NST + n0 + i] * Bm[d * NST + n0 + i] * dt * wd;
        }
    }

    const float* xp = x + ((size_t)b * SEQ + (size_t)c * cl) * DM + d;

    float xf[PF];
#pragma unroll
    for (int k = 0; k < PF; ++k) xf[k] = xp[(size_t)k * DM];
    const float* xq = xp + (size_t)PF * DM;

    int ntb = cl / PF;
    for (int t8 = 0; t8 < ntb - 1; ++t8) {
#pragma unroll
        for (int j = 0; j < PF; ++j) {
            float xv = xf[j];
            xf[j] = xq[(size_t)j * DM];          // prefetch t+PF
#pragma unroll
            for (int i = 0; i < 16; ++i) g[i] = fmaf(dA[i], g[i], xv);
        }
        xq += (size_t)PF * DM;
    }
#pragma unroll
    for (int j = 0; j < PF; ++j) {               // tail: no prefetch
        float xv = xf[j];
#pragma unroll
        for (int i = 0; i < 16; ++i) g[i] = fmaf(dA[i], g[i], xv);
    }

    float* sp = E + ((((size_t)ssm * BATCH + b) * nc + c) * NST + n0) * DM + d;
#pragma unroll
    for (int i = 0; i < 16; ++i) sp[(size_t)i * DM] = g[i];
}

// ---------------- pass 3: ssm-split wave halves; Horner-over-E prologue (no e[] temp,
// short live ranges); NO PINs (let regalloc balance arch/acc); R18 body: decoupled
// batch prefetch, full-wave primary store, combined stores batched per 8 t.
__global__ __launch_bounds__(128, 2) void ssm_pass3(
    const float* __restrict__ x,
    const float* __restrict__ dA_tbl, const float* __restrict__ Cw_tbl,
    const float* __restrict__ p_tbl,
    const float* __restrict__ E,
    float* __restrict__ out_hr, float* __restrict__ out_br, float* __restrict__ out_cb,
    int nc, int cl)
{
    int tid  = threadIdx.x;          // 128 threads = 2 waves
    int lane = tid & 63;
    int wid  = tid >> 6;
    int ssm  = lane >> 5;            // 0 -> hr, 1 -> br
    int dlo  = lane & 31;
    int bid  = blockIdx.x;           // (b*nc + c)*8 + dblk
    int dblk = bid & 7;
    int r    = bid >> 3;
    int c    = r % nc;
    int b    = r / nc;
    int d    = dblk * 64 + wid * 32 + dlo;

    // ----- chunk-INIT via Horner over local end-states (replaces pass2)
    float g[NST];
#pragma unroll
    for (int n = 0; n < NST; ++n) g[n] = 0.f;
    if (c > 0) {
        const float* pt = p_tbl + (size_t)ssm * NST * DM + d;
        float p[NST];
#pragma unroll
        for (int n = 0; n < NST; ++n) p[n] = pt[(size_t)n * DM];
        const size_t slab = (size_t)NST * DM;
        const float* ep = E + (((size_t)ssm * BATCH + b) * nc) * slab + d;
        for (int cc = 0; cc < c; ++cc) {        // g = p*g + E(cc), loads folded in
#pragma unroll
            for (int n = 0; n < NST; ++n)
                g[n] = fmaf(p[n], g[n], ep[(size_t)n * DM]);
            ep += slab;
        }
    }

    const float* dat = dA_tbl + (size_t)ssm * NST * DM + d;
    const float* cwt = Cw_tbl + (size_t)ssm * NST * DM + d;
    float dA[NST], Cw[NST];
#pragma unroll
    for (int n = 0; n < NST; ++n) {
        dA[n] = dat[(size_t)n * DM];
        Cw[n] = cwt[(size_t)n * DM];
    }

    size_t off = ((size_t)b * SEQ + (size_t)c * cl) * DM + d;
    const float* xp = x + off;
    float* po = (ssm ? out_br : out_hr) + off;   // primary: full-wave store
    float* oc = out_cb + off;                    // combined: masked to ssm==0 half

    float xf[PF];
#pragma unroll
    for (int k = 0; k < PF; ++k) xf[k] = xp[(size_t)k * DM];
    const float* xq = xp + (size_t)PF * DM;

    // DOPF: 1 -> batched reload at block top, 0 -> tail
#define BODY8(DOPF)                                                     \
    {                                                                   \
        float xc[PF];                                                   \
        _Pragma("unroll")                                               \
        for (int j = 0; j < PF; ++j) xc[j] = xf[j];                     \
        if (DOPF) {                           /* batched load issue */  \
            _Pragma("unroll")                                           \
            for (int j = 0; j < PF; ++j) xf[j] = xq[(size_t)j * DM];    \
        }                                                               \
        float yv[PF], yw[PF];                                           \
        _Pragma("unroll")                                               \
        for (int j = 0; j < PF; ++j) {                                  \
            float xv = xc[j];                                           \
            float y0 = 0.f, y1 = 0.f, y2 = 0.f, y3 = 0.f;               \
            _Pragma("unroll")                                           \
            for (int n = 0; n < NST; n += 4) {                          \
                g[n]     = fmaf(dA[n],     g[n],     xv);               \
                g[n + 1] = fmaf(dA[n + 1], g[n + 1], xv);               \
                g[n + 2] = fmaf(dA[n + 2], g[n + 2], xv);               \
                g[n + 3] = fmaf(dA[n + 3], g[n + 3], xv);               \
                y0 = fmaf(Cw[n],     g[n],     y0);                     \
                y1 = fmaf(Cw[n + 1], g[n + 1], y1);                     \
                y2 = fmaf(Cw[n + 2], g[n + 2], y2);                     \
                y3 = fmaf(Cw[n + 3], g[n + 3], y3);                     \
            }                                                           \
            float y = (y0 + y1) + (y2 + y3);                            \
            yv[j] = y;                                                  \
            yw[j] = __shfl_xor(y, 32, 64);   /* no use until batch */   \
            po[(size_t)j * DM] = y;          /* full-wave store */      \
        }                                                               \
        if (ssm == 0) {                       /* batched combined */    \
            _Pragma("unroll")                                           \
            for (int j = 0; j < PF; ++j)                                \
                oc[(size_t)j * DM] = yv[j] + yw[j];                     \
        }                                                               \
        po += (size_t)PF * DM;  oc += (size_t)PF * DM;                  \
    }

    int ntb = cl / PF;
    for (int t8 = 0; t8 < ntb - 1; ++t8) {
        BODY8(1);
        xq += (size_t)PF * DM;
    }
    BODY8(0);
#undef BODY8
}

extern "C" void kernel_launch(void* const* d_in, const int* in_sizes, int n_in,
                              void* d_out, int out_size, void* d_ws, size_t ws_size,
                              hipStream_t stream)
{
    (void)in_sizes; (void)n_in; (void)out_size;

    const float* x       = (const float*)d_in[0];
    const float* Alog_hr = (const float*)d_in[1];
    const float* B_hr    = (const float*)d_in[2];
    const float* C_hr    = (const float*)d_in[3];
    const float* ldt_hr  = (const float*)d_in[4];
    const float* Alog_br = (const float*)d_in[5];
    const float* B_br    = (const float*)d_in[6];
    const float* C_br    = (const float*)d_in[7];
    const float* ldt_br  = (const float*)d_in[8];
    const float* w_hr    = (const float*)d_in[9];
    const float* w_br    = (const float*)d_in[10];

    float* out    = (float*)d_out;
    const size_t one = (size_t)BATCH * SEQ * DM;
    float* out_hr = out;
    float* out_br = out + one;
    float* out_cb = out + 2 * one;

    float* dA_tbl = (float*)d_ws;
    float* Cw_tbl = dA_tbl + (size_t)2 * NST * DM;
    float* p_tbl  = Cw_tbl + (size_t)2 * NST * DM;
    float* E      = p_tbl  + (size_t)2 * NST * DM;

    const size_t tbl_bytes = (size_t)6 * NST * DM * sizeof(float);
    int nc = 8;      // proven; nc=16 dead (R11, R17, R20; Horner cost ~ nc^2)
    while (nc > 1 &&
           ws_size < tbl_bytes + (size_t)2 * BATCH * nc * NST * DM * sizeof(float))
        nc >>= 1;
    int cl = SEQ / nc;

    if (nc > 1) {
        int nblk1 = 2 * BATCH * (nc - 1) * 4;    // (ssm,b,c<nc-1) x 4 d-blocks of 128 (x2 nh)
        ssm_pass1<<<nblk1, 256, 0, stream>>>(x,
                                             Alog_hr, B_hr, C_hr, ldt_hr,
                                             Alog_br, B_br, C_br, ldt_br,
                                             w_hr, w_br,
                                             E, dA_tbl, Cw_tbl, p_tbl, nc, cl);
    } else {
        int total0 = 2 * NST * DM;               // fallback: tables via setup
        ssm_setup<<<total0 / 256, 256, 0, stream>>>(Alog_hr, B_hr, C_hr, ldt_hr,
                                                    Alog_br, B_br, C_br, ldt_br,
                                                    w_hr, w_br, dA_tbl, Cw_tbl);
    }

    int nblk3 = BATCH * nc * 8;                  // (b,c) x 8 d-blocks of 64 (2 waves, ssm-split)
    ssm_pass3<<<nblk3, 128, 0, stream>>>(x, dA_tbl, Cw_tbl, p_tbl, E,
                                         out_hr, out_br, out_cb, nc, cl);
}